// Round 3
// baseline (721.402 us; speedup 1.0000x reference)
//
#include <hip/hip_runtime.h>
#include <hip/hip_bf16.h>

#define NN 100000
#define NE 1600000
#define D_IN 7
#define H1 64
#define H2 32
#define NG 64
#define NB 391   // (NN+255)/256

// ---------------- in-degree histogram (int) ----------------
__global__ void k_hist(const int* __restrict__ dst, int* __restrict__ cnt) {
    int e = blockIdx.x * 256 + threadIdx.x;
    if (e < NE) atomicAdd(&cnt[dst[e]], 1);
}

// ---------------- scan stage 1: per-block sums of PADDED cnt ----------------
__global__ void k_scan1(const int* __restrict__ cnt, int* __restrict__ partials) {
    __shared__ int red[256];
    int t = threadIdx.x;
    int i = blockIdx.x * 256 + t;
    red[t] = (i < NN) ? ((cnt[i] + 7) & ~7) : 0;
    __syncthreads();
    for (int off = 128; off > 0; off >>= 1) {
        if (t < off) red[t] += red[t + off];
        __syncthreads();
    }
    if (t == 0) partials[blockIdx.x] = red[0];
}

// ---------------- scan stage 2: exclusive scan of 391 partials (1 block) ----------------
__global__ void k_scan2(int* __restrict__ partials) {
    __shared__ int s[512];
    int t = threadIdx.x;
    int val = (t < NB) ? partials[t] : 0;
    s[t] = val;
    __syncthreads();
    for (int off = 1; off < 512; off <<= 1) {
        int add = (t >= off) ? s[t - off] : 0;
        __syncthreads();
        s[t] += add;
        __syncthreads();
    }
    if (t < NB) partials[t] = s[t] - val;  // exclusive
}

// ---------------- scan stage 3: row_start (padded layout), cursor, dis ----------------
__global__ void k_scan3(const int* __restrict__ cnt, const int* __restrict__ partials,
                        int* __restrict__ row_start, int* __restrict__ cursor,
                        float* __restrict__ dis) {
    __shared__ int s[256];
    int t = threadIdx.x;
    int i = blockIdx.x * 256 + t;
    int raw = (i < NN) ? cnt[i] : 0;
    int val = (raw + 7) & ~7;
    s[t] = val;
    __syncthreads();
    for (int off = 1; off < 256; off <<= 1) {
        int add = (t >= off) ? s[t - off] : 0;
        __syncthreads();
        s[t] += add;
        __syncthreads();
    }
    if (i < NN) {
        int start = partials[blockIdx.x] + s[t] - val;
        row_start[i] = start;
        cursor[i] = start;
        dis[i] = rsqrtf((float)raw + 1.0f);
    }
}

// ---------------- fill pad slots with dummy node NN ----------------
__global__ void k_pad(const int* __restrict__ cnt, const int* __restrict__ row_start,
                      int* __restrict__ csr) {
    int i = blockIdx.x * 256 + threadIdx.x;
    if (i >= NN) return;
    int c = cnt[i], cp = (c + 7) & ~7, st = row_start[i];
    for (int j = c; j < cp; j++) csr[st + j] = NN;
}

// ---------------- CSR fill: src index only ----------------
__global__ void k_fill(const int* __restrict__ src, const int* __restrict__ dst,
                       int* __restrict__ cursor, int* __restrict__ csr) {
    int e = blockIdx.x * 256 + threadIdx.x;
    if (e >= NE) return;
    int s = src[e], d = dst[e];
    int pos = atomicAdd(&cursor[d], 1);
    csr[pos] = s;
}

// ---------------- mean pool over sorted batch ----------------
__device__ int lower_bound_i(const int* a, int n, int v) {
    int lo = 0, hi = n;
    while (lo < hi) { int mid = (lo + hi) >> 1; if (a[mid] < v) lo = mid + 1; else hi = mid; }
    return lo;
}

__global__ void k_pool(const float* __restrict__ x, const int* __restrict__ batch,
                       float* __restrict__ outp) {
    __shared__ int bounds[2];
    __shared__ float red[256 * D_IN];
    int g = blockIdx.x, t = threadIdx.x;
    if (t == 0) {
        bounds[0] = lower_bound_i(batch, NN, g);
        bounds[1] = lower_bound_i(batch, NN, g + 1);
    }
    __syncthreads();
    int s = bounds[0], e = bounds[1];
    float acc[D_IN];
#pragma unroll
    for (int k = 0; k < D_IN; k++) acc[k] = 0.f;
    for (int n = s + t; n < e; n += 256) {
#pragma unroll
        for (int k = 0; k < D_IN; k++) acc[k] += x[n * D_IN + k];
    }
#pragma unroll
    for (int k = 0; k < D_IN; k++) red[t * D_IN + k] = acc[k];
    __syncthreads();
    if (t < D_IN) {
        float sum = 0.f;
        for (int i = 0; i < 256; i++) sum += red[i * D_IN + t];
        float cnt = (float)(e - s);
        outp[g * D_IN + t] = sum / fmaxf(cnt, 1.f);
    }
}

// ---------------- y1 = dis * (x @ W1), plus zero dummy row NN ----------------
__global__ void k_mm1(const float* __restrict__ x, const float* __restrict__ W1,
                      const float* __restrict__ dis, float* __restrict__ y1) {
    __shared__ float sW[D_IN * H1];
    int t = threadIdx.x;
    for (int i = t; i < D_IN * H1; i += 256) sW[i] = W1[i];
    __syncthreads();
    int idx = blockIdx.x * 256 + t;
    if (idx < (NN + 1) * H1) {
        int n = idx >> 6, h = idx & 63;
        float a = 0.f;
        if (n < NN) {
#pragma unroll
            for (int k = 0; k < D_IN; k++) a += x[n * D_IN + k] * sW[k * H1 + h];
            a *= dis[n];
        }
        y1[idx] = a;
    }
}

// ---------------- layer-1 aggregation: wave per node, 8-way unrolled gather ----------------
__global__ __launch_bounds__(256) void k_agg1(const int* __restrict__ row_start,
                                              const int* __restrict__ cnt,
                                              const float* __restrict__ dis,
                                              const int* __restrict__ csr,
                                              const float* __restrict__ y1,
                                              float* __restrict__ agg1) {
    int node = (blockIdx.x * 256 + threadIdx.x) >> 6;
    int lane = threadIdx.x & 63;
    if (node >= NN) return;
    int start = row_start[node];
    int cp = (cnt[node] + 7) & ~7;
    const int* row = csr + start;
    float acc0 = y1[node * H1 + lane];   // self term y[d]
    float acc1 = 0.f, acc2 = 0.f, acc3 = 0.f;
    for (int j = 0; j < cp; j += 8) {
        int4 ia = *(const int4*)(row + j);      // 32B-aligned (rows padded to 8)
        int4 ib = *(const int4*)(row + j + 4);
        float v0 = y1[ia.x * H1 + lane];
        float v1 = y1[ia.y * H1 + lane];
        float v2 = y1[ia.z * H1 + lane];
        float v3 = y1[ia.w * H1 + lane];
        float v4 = y1[ib.x * H1 + lane];
        float v5 = y1[ib.y * H1 + lane];
        float v6 = y1[ib.z * H1 + lane];
        float v7 = y1[ib.w * H1 + lane];
        acc0 += v0; acc1 += v1; acc2 += v2; acc3 += v3;
        acc0 += v4; acc1 += v5; acc2 += v6; acc3 += v7;
    }
    agg1[node * H1 + lane] = dis[node] * ((acc0 + acc1) + (acc2 + acc3));
}

// ---------------- h1 = relu(agg1+b1); y23 = dis * (h1@W2 ‖ h1@W3), dummy row 0 ----------------
__global__ void k_mm2(const float* __restrict__ agg1, const float* __restrict__ b1,
                      const float* __restrict__ W2, const float* __restrict__ W3,
                      const float* __restrict__ dis, float* __restrict__ y23) {
    __shared__ float sW2[H1 * H2];
    __shared__ float sW3[H1 * H2];
    __shared__ float sb1[H1];
    __shared__ float sh[8 * H1];
    int t = threadIdx.x;
    for (int i = t; i < H1 * H2; i += 256) { sW2[i] = W2[i]; sW3[i] = W3[i]; }
    if (t < H1) sb1[t] = b1[t];
    __syncthreads();
    int base_n = blockIdx.x * 8;
    for (int i = t; i < 8 * H1; i += 256) {
        int n = base_n + (i >> 6);
        sh[i] = (n < NN) ? fmaxf(agg1[n * H1 + (i & 63)] + sb1[i & 63], 0.f) : 0.f;
    }
    __syncthreads();
    int n = base_n + (t >> 5), h = t & 31;
    if (n <= NN) {
        float a2 = 0.f, a3 = 0.f;
        const float* hr = &sh[(t >> 5) * H1];
#pragma unroll
        for (int k = 0; k < H1; k++) {
            float hv = hr[k];
            a2 += hv * sW2[k * H2 + h];
            a3 += hv * sW3[k * H2 + h];
        }
        float d = (n < NN) ? dis[n] : 0.f;
        y23[n * 64 + h]      = d * a2;
        y23[n * 64 + 32 + h] = d * a3;
    }
}

// ---------------- layer-2 aggregation + fused epilogue ----------------
// wave per node; lanes 0-31: mu (y23[..0:32]), lanes 32-63: logvar (y23[..32:64])
__global__ __launch_bounds__(256) void k_agg2(const int* __restrict__ row_start,
                                              const int* __restrict__ cnt,
                                              const float* __restrict__ dis,
                                              const int* __restrict__ csr,
                                              const float* __restrict__ y23,
                                              const float* __restrict__ b2,
                                              const float* __restrict__ b3,
                                              const float* __restrict__ eps,
                                              float* __restrict__ out_z,
                                              float* __restrict__ out_mu,
                                              float* __restrict__ out_lv) {
    int node = (blockIdx.x * 256 + threadIdx.x) >> 6;
    int lane = threadIdx.x & 63;
    if (node >= NN) return;
    int start = row_start[node];
    int cp = (cnt[node] + 7) & ~7;
    const int* row = csr + start;
    float acc0 = y23[node * 64 + lane];  // self term
    float acc1 = 0.f, acc2 = 0.f, acc3 = 0.f;
    for (int j = 0; j < cp; j += 8) {
        int4 ia = *(const int4*)(row + j);
        int4 ib = *(const int4*)(row + j + 4);
        float v0 = y23[ia.x * 64 + lane];
        float v1 = y23[ia.y * 64 + lane];
        float v2 = y23[ia.z * 64 + lane];
        float v3 = y23[ia.w * 64 + lane];
        float v4 = y23[ib.x * 64 + lane];
        float v5 = y23[ib.y * 64 + lane];
        float v6 = y23[ib.z * 64 + lane];
        float v7 = y23[ib.w * 64 + lane];
        acc0 += v0; acc1 += v1; acc2 += v2; acc3 += v3;
        acc0 += v4; acc1 += v5; acc2 += v6; acc3 += v7;
    }
    float pre = dis[node] * ((acc0 + acc1) + (acc2 + acc3));
    int ch = lane & 31;
    bool is_mu = lane < 32;
    float bias = is_mu ? b2[ch] : b3[ch];
    float val = fmaxf(pre + bias, 0.f);
    float other = __shfl(val, lane ^ 32, 64);
    int o = node * H2 + ch;
    if (is_mu) {
        out_mu[o] = val;
        out_z[o] = eps[o] * __expf(other) + val;
    } else {
        out_lv[o] = val;
    }
}

extern "C" void kernel_launch(void* const* d_in, const int* in_sizes, int n_in,
                              void* d_out, int out_size, void* d_ws, size_t ws_size,
                              hipStream_t stream) {
    const float* x   = (const float*)d_in[0];
    const int*   ei  = (const int*)d_in[1];   // [2, E]
    const int*   bat = (const int*)d_in[2];
    const float* W1  = (const float*)d_in[3];
    const float* b1  = (const float*)d_in[4];
    const float* W2  = (const float*)d_in[5];
    const float* b2  = (const float*)d_in[6];
    const float* W3  = (const float*)d_in[7];
    const float* b3  = (const float*)d_in[8];
    const float* eps = (const float*)d_in[9];

    const int* src = ei;
    const int* dst = ei + NE;

    float* out = (float*)d_out;
    float* out_z    = out;                               // [N,32]
    float* out_pool = out + (size_t)NN * H2;             // [G,7]
    float* out_mu   = out_pool + NG * D_IN;              // [N,32]
    float* out_lv   = out_mu + (size_t)NN * H2;          // [N,32]

    // workspace layout (4-byte words)
    int*    cnt       = (int*)d_ws;                      // N
    int*    row_start = cnt + NN;                        // N
    int*    cursor    = row_start + NN;                  // N
    int*    partials  = cursor + NN;                     // 512
    float*  dis       = (float*)(partials + 512);        // N
    int*    csr       = (int*)(dis + NN);                // NE + 7*NN ints (padded rows)
    float*  y1        = (float*)(csr + (NE + 7 * NN));   // (N+1)*64
    float*  agg1      = y1 + (size_t)(NN + 1) * H1;      // N*64
    float*  y23       = y1;                              // alias: y1 dead after k_agg1

    hipMemsetAsync(cnt, 0, NN * sizeof(int), stream);

    k_hist <<<(NE + 255) / 256, 256, 0, stream>>>(dst, cnt);
    k_scan1<<<NB, 256, 0, stream>>>(cnt, partials);
    k_scan2<<<1, 512, 0, stream>>>(partials);
    k_scan3<<<NB, 256, 0, stream>>>(cnt, partials, row_start, cursor, dis);
    k_pad  <<<NB, 256, 0, stream>>>(cnt, row_start, csr);
    k_fill <<<(NE + 255) / 256, 256, 0, stream>>>(src, dst, cursor, csr);

    k_pool <<<NG, 256, 0, stream>>>(x, bat, out_pool);

    k_mm1  <<<((NN + 1) * H1 + 255) / 256, 256, 0, stream>>>(x, W1, dis, y1);
    k_agg1 <<<(NN * 64 + 255) / 256, 256, 0, stream>>>(row_start, cnt, dis, csr, y1, agg1);
    k_mm2  <<<(NN + 1 + 7) / 8, 256, 0, stream>>>(agg1, b1, W2, W3, dis, y23);
    k_agg2 <<<(NN * 64 + 255) / 256, 256, 0, stream>>>(row_start, cnt, dis, csr, y23,
                                                       b2, b3, eps, out_z, out_mu, out_lv);
}

// Round 4
// 682.495 us; speedup vs baseline: 1.0570x; 1.0570x over previous
//
#include <hip/hip_runtime.h>
#include <hip/hip_bf16.h>
#include <hip/hip_fp16.h>

#define NN 100000
#define NE 1600000
#define D_IN 7
#define H1 64
#define H2 32
#define NG 64
#define NB 391   // (NN+255)/256

// ---------------- in-degree histogram (int) ----------------
__global__ void k_hist(const int* __restrict__ dst, int* __restrict__ cnt) {
    int e = blockIdx.x * 256 + threadIdx.x;
    if (e < NE) atomicAdd(&cnt[dst[e]], 1);
}

// pad row length to multiple of 4
__device__ __forceinline__ int padc(int c) { return (c + 3) & ~3; }

// ---------------- scan stage 1: per-block sums of PADDED cnt ----------------
__global__ void k_scan1(const int* __restrict__ cnt, int* __restrict__ partials) {
    __shared__ int red[256];
    int t = threadIdx.x;
    int i = blockIdx.x * 256 + t;
    red[t] = (i < NN) ? padc(cnt[i]) : 0;
    __syncthreads();
    for (int off = 128; off > 0; off >>= 1) {
        if (t < off) red[t] += red[t + off];
        __syncthreads();
    }
    if (t == 0) partials[blockIdx.x] = red[0];
}

// ---------------- scan stage 2: exclusive scan of 391 partials (1 block) ----------------
__global__ void k_scan2(int* __restrict__ partials) {
    __shared__ int s[512];
    int t = threadIdx.x;
    int val = (t < NB) ? partials[t] : 0;
    s[t] = val;
    __syncthreads();
    for (int off = 1; off < 512; off <<= 1) {
        int add = (t >= off) ? s[t - off] : 0;
        __syncthreads();
        s[t] += add;
        __syncthreads();
    }
    if (t < NB) partials[t] = s[t] - val;  // exclusive
}

// ---------------- scan stage 3: row_start (padded layout), cursor, dis ----------------
__global__ void k_scan3(const int* __restrict__ cnt, const int* __restrict__ partials,
                        int* __restrict__ row_start, int* __restrict__ cursor,
                        float* __restrict__ dis) {
    __shared__ int s[256];
    int t = threadIdx.x;
    int i = blockIdx.x * 256 + t;
    int raw = (i < NN) ? cnt[i] : 0;
    int val = padc(raw);
    s[t] = val;
    __syncthreads();
    for (int off = 1; off < 256; off <<= 1) {
        int add = (t >= off) ? s[t - off] : 0;
        __syncthreads();
        s[t] += add;
        __syncthreads();
    }
    if (i < NN) {
        int start = partials[blockIdx.x] + s[t] - val;
        row_start[i] = start;
        cursor[i] = start;
        dis[i] = rsqrtf((float)raw + 1.0f);
    }
}

// ---------------- fill pad slots with dummy node NN (zero row) ----------------
__global__ void k_pad(const int* __restrict__ cnt, const int* __restrict__ row_start,
                      int* __restrict__ csr) {
    int i = blockIdx.x * 256 + threadIdx.x;
    if (i >= NN) return;
    int c = cnt[i], cp = padc(c), st = row_start[i];
    for (int j = c; j < cp; j++) csr[st + j] = NN;
}

// ---------------- CSR fill: src index only ----------------
__global__ void k_fill(const int* __restrict__ src, const int* __restrict__ dst,
                       int* __restrict__ cursor, int* __restrict__ csr) {
    int e = blockIdx.x * 256 + threadIdx.x;
    if (e >= NE) return;
    int s = src[e], d = dst[e];
    int pos = atomicAdd(&cursor[d], 1);
    csr[pos] = s;
}

// ---------------- mean pool over sorted batch ----------------
__device__ int lower_bound_i(const int* a, int n, int v) {
    int lo = 0, hi = n;
    while (lo < hi) { int mid = (lo + hi) >> 1; if (a[mid] < v) lo = mid + 1; else hi = mid; }
    return lo;
}

__global__ void k_pool(const float* __restrict__ x, const int* __restrict__ batch,
                       float* __restrict__ outp) {
    __shared__ int bounds[2];
    __shared__ float red[256 * D_IN];
    int g = blockIdx.x, t = threadIdx.x;
    if (t == 0) {
        bounds[0] = lower_bound_i(batch, NN, g);
        bounds[1] = lower_bound_i(batch, NN, g + 1);
    }
    __syncthreads();
    int s = bounds[0], e = bounds[1];
    float acc[D_IN];
#pragma unroll
    for (int k = 0; k < D_IN; k++) acc[k] = 0.f;
    for (int n = s + t; n < e; n += 256) {
#pragma unroll
        for (int k = 0; k < D_IN; k++) acc[k] += x[n * D_IN + k];
    }
#pragma unroll
    for (int k = 0; k < D_IN; k++) red[t * D_IN + k] = acc[k];
    __syncthreads();
    if (t < D_IN) {
        float sum = 0.f;
        for (int i = 0; i < 256; i++) sum += red[i * D_IN + t];
        float cnt = (float)(e - s);
        outp[g * D_IN + t] = sum / fmaxf(cnt, 1.f);
    }
}

// ---------------- y1h = fp16( dis * (x @ W1) ), plus zero dummy row NN ----------------
__global__ void k_mm1(const float* __restrict__ x, const float* __restrict__ W1,
                      const float* __restrict__ dis, __half* __restrict__ y1h) {
    __shared__ float sW[D_IN * H1];
    int t = threadIdx.x;
    for (int i = t; i < D_IN * H1; i += 256) sW[i] = W1[i];
    __syncthreads();
    int idx = blockIdx.x * 256 + t;
    if (idx < (NN + 1) * H1) {
        int n = idx >> 6, h = idx & 63;
        float a = 0.f;
        if (n < NN) {
#pragma unroll
            for (int k = 0; k < D_IN; k++) a += x[n * D_IN + k] * sW[k * H1 + h];
            a *= dis[n];
        }
        y1h[idx] = __float2half(a);
    }
}

// ---------------- layer-1 aggregation: wave per node, fp16 gather, 8-deep MLP ----------------
__global__ __launch_bounds__(256) void k_agg1(const int* __restrict__ row_start,
                                              const int* __restrict__ cnt,
                                              const float* __restrict__ dis,
                                              const int* __restrict__ csr,
                                              const __half* __restrict__ y1h,
                                              float* __restrict__ agg1) {
    int node = (blockIdx.x * 256 + threadIdx.x) >> 6;
    int lane = threadIdx.x & 63;
    if (node >= NN) return;
    int start = row_start[node];
    int cp = padc(cnt[node]);
    const int* row = csr + start;
    float acc0 = __half2float(y1h[node * H1 + lane]);  // self term
    float acc1 = 0.f, acc2 = 0.f, acc3 = 0.f;
    int j = 0;
    for (; j + 8 <= cp; j += 8) {
        int4 ia = *(const int4*)(row + j);       // rows 16B-aligned (pad-4)
        int4 ib = *(const int4*)(row + j + 4);
        float v0 = __half2float(y1h[ia.x * H1 + lane]);
        float v1 = __half2float(y1h[ia.y * H1 + lane]);
        float v2 = __half2float(y1h[ia.z * H1 + lane]);
        float v3 = __half2float(y1h[ia.w * H1 + lane]);
        float v4 = __half2float(y1h[ib.x * H1 + lane]);
        float v5 = __half2float(y1h[ib.y * H1 + lane]);
        float v6 = __half2float(y1h[ib.z * H1 + lane]);
        float v7 = __half2float(y1h[ib.w * H1 + lane]);
        acc0 += v0; acc1 += v1; acc2 += v2; acc3 += v3;
        acc0 += v4; acc1 += v5; acc2 += v6; acc3 += v7;
    }
    if (j < cp) {  // 4-step tail
        int4 ia = *(const int4*)(row + j);
        acc0 += __half2float(y1h[ia.x * H1 + lane]);
        acc1 += __half2float(y1h[ia.y * H1 + lane]);
        acc2 += __half2float(y1h[ia.z * H1 + lane]);
        acc3 += __half2float(y1h[ia.w * H1 + lane]);
    }
    agg1[node * H1 + lane] = dis[node] * ((acc0 + acc1) + (acc2 + acc3));
}

// ---------------- h1 = relu(agg1+b1); y23h = fp16( dis * (h1@W2 ‖ h1@W3) ) ----------------
__global__ void k_mm2(const float* __restrict__ agg1, const float* __restrict__ b1,
                      const float* __restrict__ W2, const float* __restrict__ W3,
                      const float* __restrict__ dis, __half* __restrict__ y23h) {
    __shared__ float sW2[H1 * H2];
    __shared__ float sW3[H1 * H2];
    __shared__ float sb1[H1];
    __shared__ float sh[8 * H1];
    int t = threadIdx.x;
    for (int i = t; i < H1 * H2; i += 256) { sW2[i] = W2[i]; sW3[i] = W3[i]; }
    if (t < H1) sb1[t] = b1[t];
    __syncthreads();
    int base_n = blockIdx.x * 8;
    for (int i = t; i < 8 * H1; i += 256) {
        int n = base_n + (i >> 6);
        sh[i] = (n < NN) ? fmaxf(agg1[n * H1 + (i & 63)] + sb1[i & 63], 0.f) : 0.f;
    }
    __syncthreads();
    int n = base_n + (t >> 5), h = t & 31;
    if (n <= NN) {
        float a2 = 0.f, a3 = 0.f;
        const float* hr = &sh[(t >> 5) * H1];
#pragma unroll
        for (int k = 0; k < H1; k++) {
            float hv = hr[k];
            a2 += hv * sW2[k * H2 + h];
            a3 += hv * sW3[k * H2 + h];
        }
        float d = (n < NN) ? dis[n] : 0.f;
        y23h[n * 64 + h]      = __float2half(d * a2);
        y23h[n * 64 + 32 + h] = __float2half(d * a3);
    }
}

// ---------------- layer-2 aggregation + fused epilogue ----------------
__global__ __launch_bounds__(256) void k_agg2(const int* __restrict__ row_start,
                                              const int* __restrict__ cnt,
                                              const float* __restrict__ dis,
                                              const int* __restrict__ csr,
                                              const __half* __restrict__ y23h,
                                              const float* __restrict__ b2,
                                              const float* __restrict__ b3,
                                              const float* __restrict__ eps,
                                              float* __restrict__ out_z,
                                              float* __restrict__ out_mu,
                                              float* __restrict__ out_lv) {
    int node = (blockIdx.x * 256 + threadIdx.x) >> 6;
    int lane = threadIdx.x & 63;
    if (node >= NN) return;
    int start = row_start[node];
    int cp = padc(cnt[node]);
    const int* row = csr + start;
    float acc0 = __half2float(y23h[node * 64 + lane]);  // self term
    float acc1 = 0.f, acc2 = 0.f, acc3 = 0.f;
    int j = 0;
    for (; j + 8 <= cp; j += 8) {
        int4 ia = *(const int4*)(row + j);
        int4 ib = *(const int4*)(row + j + 4);
        float v0 = __half2float(y23h[ia.x * 64 + lane]);
        float v1 = __half2float(y23h[ia.y * 64 + lane]);
        float v2 = __half2float(y23h[ia.z * 64 + lane]);
        float v3 = __half2float(y23h[ia.w * 64 + lane]);
        float v4 = __half2float(y23h[ib.x * 64 + lane]);
        float v5 = __half2float(y23h[ib.y * 64 + lane]);
        float v6 = __half2float(y23h[ib.z * 64 + lane]);
        float v7 = __half2float(y23h[ib.w * 64 + lane]);
        acc0 += v0; acc1 += v1; acc2 += v2; acc3 += v3;
        acc0 += v4; acc1 += v5; acc2 += v6; acc3 += v7;
    }
    if (j < cp) {
        int4 ia = *(const int4*)(row + j);
        acc0 += __half2float(y23h[ia.x * 64 + lane]);
        acc1 += __half2float(y23h[ia.y * 64 + lane]);
        acc2 += __half2float(y23h[ia.z * 64 + lane]);
        acc3 += __half2float(y23h[ia.w * 64 + lane]);
    }
    float pre = dis[node] * ((acc0 + acc1) + (acc2 + acc3));
    int ch = lane & 31;
    bool is_mu = lane < 32;
    float bias = is_mu ? b2[ch] : b3[ch];
    float val = fmaxf(pre + bias, 0.f);
    float other = __shfl(val, lane ^ 32, 64);
    int o = node * H2 + ch;
    if (is_mu) {
        out_mu[o] = val;
        out_z[o] = eps[o] * __expf(other) + val;
    } else {
        out_lv[o] = val;
    }
}

extern "C" void kernel_launch(void* const* d_in, const int* in_sizes, int n_in,
                              void* d_out, int out_size, void* d_ws, size_t ws_size,
                              hipStream_t stream) {
    const float* x   = (const float*)d_in[0];
    const int*   ei  = (const int*)d_in[1];   // [2, E]
    const int*   bat = (const int*)d_in[2];
    const float* W1  = (const float*)d_in[3];
    const float* b1  = (const float*)d_in[4];
    const float* W2  = (const float*)d_in[5];
    const float* b2  = (const float*)d_in[6];
    const float* W3  = (const float*)d_in[7];
    const float* b3  = (const float*)d_in[8];
    const float* eps = (const float*)d_in[9];

    const int* src = ei;
    const int* dst = ei + NE;

    float* out = (float*)d_out;
    float* out_z    = out;                               // [N,32]
    float* out_pool = out + (size_t)NN * H2;             // [G,7]
    float* out_mu   = out_pool + NG * D_IN;              // [N,32]
    float* out_lv   = out_mu + (size_t)NN * H2;          // [N,32]

    // workspace layout (4-byte words)
    int*    cnt       = (int*)d_ws;                      // N
    int*    row_start = cnt + NN;                        // N
    int*    cursor    = row_start + NN;                  // N
    int*    partials  = cursor + NN;                     // 512
    float*  dis       = (float*)(partials + 512);        // N
    int*    csr       = (int*)(dis + NN);                // NE + 3*NN ints (pad-4 rows)
    __half* y1h       = (__half*)(csr + (NE + 3 * NN));  // (N+1)*64 halves
    float*  agg1      = (float*)(y1h + (size_t)(NN + 1) * H1);  // N*64 floats
    __half* y23h      = y1h;                             // alias: y1h dead after k_agg1

    hipMemsetAsync(cnt, 0, NN * sizeof(int), stream);

    k_hist <<<(NE + 255) / 256, 256, 0, stream>>>(dst, cnt);
    k_scan1<<<NB, 256, 0, stream>>>(cnt, partials);
    k_scan2<<<1, 512, 0, stream>>>(partials);
    k_scan3<<<NB, 256, 0, stream>>>(cnt, partials, row_start, cursor, dis);
    k_pad  <<<NB, 256, 0, stream>>>(cnt, row_start, csr);
    k_fill <<<(NE + 255) / 256, 256, 0, stream>>>(src, dst, cursor, csr);

    k_pool <<<NG, 256, 0, stream>>>(x, bat, out_pool);

    k_mm1  <<<((NN + 1) * H1 + 255) / 256, 256, 0, stream>>>(x, W1, dis, y1h);
    k_agg1 <<<(NN * 64 + 255) / 256, 256, 0, stream>>>(row_start, cnt, dis, csr, y1h, agg1);
    k_mm2  <<<(NN + 1 + 7) / 8, 256, 0, stream>>>(agg1, b1, W2, W3, dis, y23h);
    k_agg2 <<<(NN * 64 + 255) / 256, 256, 0, stream>>>(row_start, cnt, dis, csr, y23h,
                                                       b2, b3, eps, out_z, out_mu, out_lv);
}

// Round 5
// 637.537 us; speedup vs baseline: 1.1315x; 1.0705x over previous
//
#include <hip/hip_runtime.h>
#include <hip/hip_bf16.h>
#include <hip/hip_fp16.h>

#define NN 100000
#define NE 1600000
#define D_IN 7
#define H1 64
#define H2 32
#define NG 64
#define NB 391   // (NN+255)/256

// ---------------- in-degree histogram (int) ----------------
__global__ void k_hist(const int* __restrict__ dst, int* __restrict__ cnt) {
    int e = blockIdx.x * 256 + threadIdx.x;
    if (e < NE) atomicAdd(&cnt[dst[e]], 1);
}

// ---------------- scan stage 1: per-block sums of cnt ----------------
__global__ void k_scan1(const int* __restrict__ cnt, int* __restrict__ partials) {
    __shared__ int red[256];
    int t = threadIdx.x;
    int i = blockIdx.x * 256 + t;
    red[t] = (i < NN) ? cnt[i] : 0;
    __syncthreads();
    for (int off = 128; off > 0; off >>= 1) {
        if (t < off) red[t] += red[t + off];
        __syncthreads();
    }
    if (t == 0) partials[blockIdx.x] = red[0];
}

// ---------------- scan stage 2: exclusive scan of 391 partials (1 block) ----------------
__global__ void k_scan2(int* __restrict__ partials) {
    __shared__ int s[512];
    int t = threadIdx.x;
    int val = (t < NB) ? partials[t] : 0;
    s[t] = val;
    __syncthreads();
    for (int off = 1; off < 512; off <<= 1) {
        int add = (t >= off) ? s[t - off] : 0;
        __syncthreads();
        s[t] += add;
        __syncthreads();
    }
    if (t < NB) partials[t] = s[t] - val;  // exclusive
}

// ---------------- scan stage 3: row_start, cursor, dis ----------------
__global__ void k_scan3(const int* __restrict__ cnt, const int* __restrict__ partials,
                        int* __restrict__ row_start, int* __restrict__ cursor,
                        float* __restrict__ dis) {
    __shared__ int s[256];
    int t = threadIdx.x;
    int i = blockIdx.x * 256 + t;
    int val = (i < NN) ? cnt[i] : 0;
    s[t] = val;
    __syncthreads();
    for (int off = 1; off < 256; off <<= 1) {
        int add = (t >= off) ? s[t - off] : 0;
        __syncthreads();
        s[t] += add;
        __syncthreads();
    }
    if (i < NN) {
        int start = partials[blockIdx.x] + s[t] - val;
        row_start[i] = start;
        cursor[i] = start;
        dis[i] = rsqrtf((float)val + 1.0f);
    }
}

// ---------------- CSR fill: src index only ----------------
__global__ void k_fill(const int* __restrict__ src, const int* __restrict__ dst,
                       int* __restrict__ cursor, int* __restrict__ csr) {
    int e = blockIdx.x * 256 + threadIdx.x;
    if (e >= NE) return;
    int s = src[e], d = dst[e];
    int pos = atomicAdd(&cursor[d], 1);
    csr[pos] = s;
}

// ---------------- mean pool over sorted batch ----------------
__device__ int lower_bound_i(const int* a, int n, int v) {
    int lo = 0, hi = n;
    while (lo < hi) { int mid = (lo + hi) >> 1; if (a[mid] < v) lo = mid + 1; else hi = mid; }
    return lo;
}

__global__ void k_pool(const float* __restrict__ x, const int* __restrict__ batch,
                       float* __restrict__ outp) {
    __shared__ int bounds[2];
    __shared__ float red[256 * D_IN];
    int g = blockIdx.x, t = threadIdx.x;
    if (t == 0) {
        bounds[0] = lower_bound_i(batch, NN, g);
        bounds[1] = lower_bound_i(batch, NN, g + 1);
    }
    __syncthreads();
    int s = bounds[0], e = bounds[1];
    float acc[D_IN];
#pragma unroll
    for (int k = 0; k < D_IN; k++) acc[k] = 0.f;
    for (int n = s + t; n < e; n += 256) {
#pragma unroll
        for (int k = 0; k < D_IN; k++) acc[k] += x[n * D_IN + k];
    }
#pragma unroll
    for (int k = 0; k < D_IN; k++) red[t * D_IN + k] = acc[k];
    __syncthreads();
    if (t < D_IN) {
        float sum = 0.f;
        for (int i = 0; i < 256; i++) sum += red[i * D_IN + t];
        float cnt = (float)(e - s);
        outp[g * D_IN + t] = sum / fmaxf(cnt, 1.f);
    }
}

// ---------------- y1h = fp16( dis * (x @ W1) ) ----------------
__global__ void k_mm1(const float* __restrict__ x, const float* __restrict__ W1,
                      const float* __restrict__ dis, __half* __restrict__ y1h) {
    __shared__ float sW[D_IN * H1];
    int t = threadIdx.x;
    for (int i = t; i < D_IN * H1; i += 256) sW[i] = W1[i];
    __syncthreads();
    int idx = blockIdx.x * 256 + t;
    if (idx < NN * H1) {
        int n = idx >> 6, h = idx & 63;
        float a = 0.f;
#pragma unroll
        for (int k = 0; k < D_IN; k++) a += x[n * D_IN + k] * sW[k * H1 + h];
        y1h[idx] = __float2half(a * dis[n]);
    }
}

// ---------------- layer-1 aggregation: wave per node, simple gather loop ----------------
// agg1[d] = dis_d * ( y[d] + sum_{s in N(d)} y[s] ),  y = dis * xw1
__global__ __launch_bounds__(256) void k_agg1(const int* __restrict__ row_start,
                                              const int* __restrict__ cnt,
                                              const float* __restrict__ dis,
                                              const int* __restrict__ csr,
                                              const __half* __restrict__ y1h,
                                              float* __restrict__ agg1) {
    int node = (blockIdx.x * 256 + threadIdx.x) >> 6;
    int lane = threadIdx.x & 63;
    if (node >= NN) return;
    int start = row_start[node];
    int c = cnt[node];
    float acc = __half2float(y1h[node * H1 + lane]);  // self term
    for (int j = 0; j < c; j++) {
        int s = csr[start + j];                       // broadcast 4B load
        acc += __half2float(y1h[s * H1 + lane]);      // 128B coalesced gather
    }
    agg1[node * H1 + lane] = dis[node] * acc;
}

// ---------------- h1 = relu(agg1+b1); y23h = fp16( dis * (h1@W2 ‖ h1@W3) ) ----------------
__global__ void k_mm2(const float* __restrict__ agg1, const float* __restrict__ b1,
                      const float* __restrict__ W2, const float* __restrict__ W3,
                      const float* __restrict__ dis, __half* __restrict__ y23h) {
    __shared__ float sW2[H1 * H2];
    __shared__ float sW3[H1 * H2];
    __shared__ float sb1[H1];
    __shared__ float sh[8 * H1];
    int t = threadIdx.x;
    for (int i = t; i < H1 * H2; i += 256) { sW2[i] = W2[i]; sW3[i] = W3[i]; }
    if (t < H1) sb1[t] = b1[t];
    __syncthreads();
    int base_n = blockIdx.x * 8;
    for (int i = t; i < 8 * H1; i += 256) {
        int n = base_n + (i >> 6);
        sh[i] = (n < NN) ? fmaxf(agg1[n * H1 + (i & 63)] + sb1[i & 63], 0.f) : 0.f;
    }
    __syncthreads();
    int n = base_n + (t >> 5), h = t & 31;
    if (n < NN) {
        float a2 = 0.f, a3 = 0.f;
        const float* hr = &sh[(t >> 5) * H1];
#pragma unroll
        for (int k = 0; k < H1; k++) {
            float hv = hr[k];
            a2 += hv * sW2[k * H2 + h];
            a3 += hv * sW3[k * H2 + h];
        }
        float d = dis[n];
        y23h[n * 64 + h]      = __float2half(d * a2);
        y23h[n * 64 + 32 + h] = __float2half(d * a3);
    }
}

// ---------------- layer-2 aggregation + fused epilogue ----------------
// wave per node; lanes 0-31: mu, lanes 32-63: logvar (interleaved y23h rows)
__global__ __launch_bounds__(256) void k_agg2(const int* __restrict__ row_start,
                                              const int* __restrict__ cnt,
                                              const float* __restrict__ dis,
                                              const int* __restrict__ csr,
                                              const __half* __restrict__ y23h,
                                              const float* __restrict__ b2,
                                              const float* __restrict__ b3,
                                              const float* __restrict__ eps,
                                              float* __restrict__ out_z,
                                              float* __restrict__ out_mu,
                                              float* __restrict__ out_lv) {
    int node = (blockIdx.x * 256 + threadIdx.x) >> 6;
    int lane = threadIdx.x & 63;
    if (node >= NN) return;
    int start = row_start[node];
    int c = cnt[node];
    float acc = __half2float(y23h[node * 64 + lane]);  // self term
    for (int j = 0; j < c; j++) {
        int s = csr[start + j];
        acc += __half2float(y23h[s * 64 + lane]);
    }
    float pre = dis[node] * acc;
    int ch = lane & 31;
    bool is_mu = lane < 32;
    float bias = is_mu ? b2[ch] : b3[ch];
    float val = fmaxf(pre + bias, 0.f);
    float other = __shfl(val, lane ^ 32, 64);
    int o = node * H2 + ch;
    if (is_mu) {
        out_mu[o] = val;
        out_z[o] = eps[o] * __expf(other) + val;
    } else {
        out_lv[o] = val;
    }
}

extern "C" void kernel_launch(void* const* d_in, const int* in_sizes, int n_in,
                              void* d_out, int out_size, void* d_ws, size_t ws_size,
                              hipStream_t stream) {
    const float* x   = (const float*)d_in[0];
    const int*   ei  = (const int*)d_in[1];   // [2, E]
    const int*   bat = (const int*)d_in[2];
    const float* W1  = (const float*)d_in[3];
    const float* b1  = (const float*)d_in[4];
    const float* W2  = (const float*)d_in[5];
    const float* b2  = (const float*)d_in[6];
    const float* W3  = (const float*)d_in[7];
    const float* b3  = (const float*)d_in[8];
    const float* eps = (const float*)d_in[9];

    const int* src = ei;
    const int* dst = ei + NE;

    float* out = (float*)d_out;
    float* out_z    = out;                               // [N,32]
    float* out_pool = out + (size_t)NN * H2;             // [G,7]
    float* out_mu   = out_pool + NG * D_IN;              // [N,32]
    float* out_lv   = out_mu + (size_t)NN * H2;          // [N,32]

    // workspace layout (4-byte words)
    int*    cnt       = (int*)d_ws;                      // N
    int*    row_start = cnt + NN;                        // N
    int*    cursor    = row_start + NN;                  // N
    int*    partials  = cursor + NN;                     // 512
    float*  dis       = (float*)(partials + 512);        // N
    int*    csr       = (int*)(dis + NN);                // NE ints
    __half* y1h       = (__half*)(csr + NE);             // N*64 halves
    float*  agg1      = (float*)(y1h + (size_t)NN * H1); // N*64 floats
    __half* y23h      = y1h;                             // alias: y1h dead after k_agg1

    hipMemsetAsync(cnt, 0, NN * sizeof(int), stream);

    k_hist <<<(NE + 255) / 256, 256, 0, stream>>>(dst, cnt);
    k_scan1<<<NB, 256, 0, stream>>>(cnt, partials);
    k_scan2<<<1, 512, 0, stream>>>(partials);
    k_scan3<<<NB, 256, 0, stream>>>(cnt, partials, row_start, cursor, dis);
    k_fill <<<(NE + 255) / 256, 256, 0, stream>>>(src, dst, cursor, csr);

    k_pool <<<NG, 256, 0, stream>>>(x, bat, out_pool);

    k_mm1  <<<(NN * H1 + 255) / 256, 256, 0, stream>>>(x, W1, dis, y1h);
    k_agg1 <<<(NN * 64 + 255) / 256, 256, 0, stream>>>(row_start, cnt, dis, csr, y1h, agg1);
    k_mm2  <<<(NN + 7) / 8, 256, 0, stream>>>(agg1, b1, W2, W3, dis, y23h);
    k_agg2 <<<(NN * 64 + 255) / 256, 256, 0, stream>>>(row_start, cnt, dis, csr, y23h,
                                                       b2, b3, eps, out_z, out_mu, out_lv);
}

// Round 6
// 451.492 us; speedup vs baseline: 1.5978x; 1.4121x over previous
//
#include <hip/hip_runtime.h>
#include <hip/hip_bf16.h>
#include <hip/hip_fp16.h>

#define NN 100000
#define NE 1600000
#define D_IN 7
#define H1 64
#define H2 32
#define NG 64
#define NB 391   // (NN+255)/256

// ---------------- in-degree histogram (int) ----------------
__global__ void k_hist(const int* __restrict__ dst, int* __restrict__ cnt) {
    int e = blockIdx.x * 256 + threadIdx.x;
    if (e < NE) atomicAdd(&cnt[dst[e]], 1);
}

// ---------------- scan stage 1: per-block sums of cnt ----------------
__global__ void k_scan1(const int* __restrict__ cnt, int* __restrict__ partials) {
    __shared__ int red[256];
    int t = threadIdx.x;
    int i = blockIdx.x * 256 + t;
    red[t] = (i < NN) ? cnt[i] : 0;
    __syncthreads();
    for (int off = 128; off > 0; off >>= 1) {
        if (t < off) red[t] += red[t + off];
        __syncthreads();
    }
    if (t == 0) partials[blockIdx.x] = red[0];
}

// ---------------- scan stage 2: exclusive scan of 391 partials (1 block) ----------------
__global__ void k_scan2(int* __restrict__ partials) {
    __shared__ int s[512];
    int t = threadIdx.x;
    int val = (t < NB) ? partials[t] : 0;
    s[t] = val;
    __syncthreads();
    for (int off = 1; off < 512; off <<= 1) {
        int add = (t >= off) ? s[t - off] : 0;
        __syncthreads();
        s[t] += add;
        __syncthreads();
    }
    if (t < NB) partials[t] = s[t] - val;  // exclusive
}

// ---------------- scan stage 3: row_start, cursor, dis ----------------
__global__ void k_scan3(const int* __restrict__ cnt, const int* __restrict__ partials,
                        int* __restrict__ row_start, int* __restrict__ cursor,
                        float* __restrict__ dis) {
    __shared__ int s[256];
    int t = threadIdx.x;
    int i = blockIdx.x * 256 + t;
    int val = (i < NN) ? cnt[i] : 0;
    s[t] = val;
    __syncthreads();
    for (int off = 1; off < 256; off <<= 1) {
        int add = (t >= off) ? s[t - off] : 0;
        __syncthreads();
        s[t] += add;
        __syncthreads();
    }
    if (i < NN) {
        int start = partials[blockIdx.x] + s[t] - val;
        row_start[i] = start;
        cursor[i] = start;
        dis[i] = rsqrtf((float)val + 1.0f);
    }
}

// ---------------- CSR fill: src index only ----------------
__global__ void k_fill(const int* __restrict__ src, const int* __restrict__ dst,
                       int* __restrict__ cursor, int* __restrict__ csr) {
    int e = blockIdx.x * 256 + threadIdx.x;
    if (e >= NE) return;
    int s = src[e], d = dst[e];
    int pos = atomicAdd(&cursor[d], 1);
    csr[pos] = s;
}

// ---------------- mean pool over sorted batch ----------------
__device__ int lower_bound_i(const int* a, int n, int v) {
    int lo = 0, hi = n;
    while (lo < hi) { int mid = (lo + hi) >> 1; if (a[mid] < v) lo = mid + 1; else hi = mid; }
    return lo;
}

__global__ void k_pool(const float* __restrict__ x, const int* __restrict__ batch,
                       float* __restrict__ outp) {
    __shared__ int bounds[2];
    __shared__ float red[256 * D_IN];
    int g = blockIdx.x, t = threadIdx.x;
    if (t == 0) {
        bounds[0] = lower_bound_i(batch, NN, g);
        bounds[1] = lower_bound_i(batch, NN, g + 1);
    }
    __syncthreads();
    int s = bounds[0], e = bounds[1];
    float acc[D_IN];
#pragma unroll
    for (int k = 0; k < D_IN; k++) acc[k] = 0.f;
    for (int n = s + t; n < e; n += 256) {
#pragma unroll
        for (int k = 0; k < D_IN; k++) acc[k] += x[n * D_IN + k];
    }
#pragma unroll
    for (int k = 0; k < D_IN; k++) red[t * D_IN + k] = acc[k];
    __syncthreads();
    if (t < D_IN) {
        float sum = 0.f;
        for (int i = 0; i < 256; i++) sum += red[i * D_IN + t];
        float cnt = (float)(e - s);
        outp[g * D_IN + t] = sum / fmaxf(cnt, 1.f);
    }
}

// ---------------- y1h = fp16( dis * (x @ W1) ) ----------------
__global__ void k_mm1(const float* __restrict__ x, const float* __restrict__ W1,
                      const float* __restrict__ dis, __half* __restrict__ y1h) {
    __shared__ float sW[D_IN * H1];
    int t = threadIdx.x;
    for (int i = t; i < D_IN * H1; i += 256) sW[i] = W1[i];
    __syncthreads();
    int idx = blockIdx.x * 256 + t;
    if (idx < NN * H1) {
        int n = idx >> 6, h = idx & 63;
        float a = 0.f;
#pragma unroll
        for (int k = 0; k < D_IN; k++) a += x[n * D_IN + k] * sW[k * H1 + h];
        y1h[idx] = __float2half(a * dis[n]);
    }
}

// convert 4 packed halves (as float2 raw) to float4
__device__ __forceinline__ float4 h4_to_f4(float2 r) {
    __half2 h0 = *reinterpret_cast<__half2*>(&r.x);
    __half2 h1 = *reinterpret_cast<__half2*>(&r.y);
    float2 f0 = __half22float2(h0);
    float2 f1 = __half22float2(h1);
    return make_float4(f0.x, f0.y, f1.x, f1.y);
}

// ---------------- layer-1 aggregation: wave per node, 4 edges/instr ----------------
// lane layout: g = lane>>4 (edge group), l15 = lane&15 (channel quad: ch 4*l15..+3)
__global__ __launch_bounds__(256) void k_agg1(const int* __restrict__ row_start,
                                              const int* __restrict__ cnt,
                                              const float* __restrict__ dis,
                                              const int* __restrict__ csr,
                                              const __half* __restrict__ y1h,
                                              float* __restrict__ agg1) {
    int node = (blockIdx.x * 256 + threadIdx.x) >> 6;
    int lane = threadIdx.x & 63;
    if (node >= NN) return;
    int g = lane >> 4, l15 = lane & 15;
    int start = row_start[node];
    int c = cnt[node];
    const float2* yb = (const float2*)y1h;   // row = 16 float2 (4 halves each)
    float4 a0 = make_float4(0.f, 0.f, 0.f, 0.f);
    float4 a1 = make_float4(0.f, 0.f, 0.f, 0.f);
    int j = 0;
    for (; j + 8 <= c; j += 8) {             // 8 edges per iter, 2 gathers in flight
        int s0 = csr[start + j + g];
        int s1 = csr[start + j + 4 + g];
        float2 r0 = yb[(size_t)s0 * 16 + l15];
        float2 r1 = yb[(size_t)s1 * 16 + l15];
        float4 v0 = h4_to_f4(r0), v1 = h4_to_f4(r1);
        a0.x += v0.x; a0.y += v0.y; a0.z += v0.z; a0.w += v0.w;
        a1.x += v1.x; a1.y += v1.y; a1.z += v1.z; a1.w += v1.w;
    }
    for (; j < c; j += 4) {                  // predicated tail (≤ 1 iter of 4)
        int pos = start + j + g;
        bool valid = (j + g) < c;
        pos = pos < NE ? pos : NE - 1;
        int s = csr[pos];
        s = valid ? s : node;
        float4 v = h4_to_f4(yb[(size_t)s * 16 + l15]);
        a0.x += valid ? v.x : 0.f; a0.y += valid ? v.y : 0.f;
        a0.z += valid ? v.z : 0.f; a0.w += valid ? v.w : 0.f;
    }
    float4 tot = make_float4(a0.x + a1.x, a0.y + a1.y, a0.z + a1.z, a0.w + a1.w);
    // butterfly across the 4 groups
    tot.x += __shfl_xor(tot.x, 16, 64); tot.x += __shfl_xor(tot.x, 32, 64);
    tot.y += __shfl_xor(tot.y, 16, 64); tot.y += __shfl_xor(tot.y, 32, 64);
    tot.z += __shfl_xor(tot.z, 16, 64); tot.z += __shfl_xor(tot.z, 32, 64);
    tot.w += __shfl_xor(tot.w, 16, 64); tot.w += __shfl_xor(tot.w, 32, 64);
    // self term + scale
    float4 sv = h4_to_f4(yb[(size_t)node * 16 + l15]);
    float dn = dis[node];
    float4 outv = make_float4(dn * (tot.x + sv.x), dn * (tot.y + sv.y),
                              dn * (tot.z + sv.z), dn * (tot.w + sv.w));
    if (g == 0) ((float4*)(agg1 + (size_t)node * 64))[l15] = outv;
}

// ---------------- h1 = relu(agg1+b1); y23h = fp16( dis * (h1@W2 ‖ h1@W3) ) ----------------
__global__ void k_mm2(const float* __restrict__ agg1, const float* __restrict__ b1,
                      const float* __restrict__ W2, const float* __restrict__ W3,
                      const float* __restrict__ dis, __half* __restrict__ y23h) {
    __shared__ float sW2[H1 * H2];
    __shared__ float sW3[H1 * H2];
    __shared__ float sb1[H1];
    __shared__ float sh[8 * H1];
    int t = threadIdx.x;
    for (int i = t; i < H1 * H2; i += 256) { sW2[i] = W2[i]; sW3[i] = W3[i]; }
    if (t < H1) sb1[t] = b1[t];
    __syncthreads();
    int base_n = blockIdx.x * 8;
    for (int i = t; i < 8 * H1; i += 256) {
        int n = base_n + (i >> 6);
        sh[i] = (n < NN) ? fmaxf(agg1[n * H1 + (i & 63)] + sb1[i & 63], 0.f) : 0.f;
    }
    __syncthreads();
    int n = base_n + (t >> 5), h = t & 31;
    if (n < NN) {
        float a2 = 0.f, a3 = 0.f;
        const float* hr = &sh[(t >> 5) * H1];
#pragma unroll
        for (int k = 0; k < H1; k++) {
            float hv = hr[k];
            a2 += hv * sW2[k * H2 + h];
            a3 += hv * sW3[k * H2 + h];
        }
        float d = dis[n];
        y23h[n * 64 + h]      = __float2half(d * a2);
        y23h[n * 64 + 32 + h] = __float2half(d * a3);
    }
}

// ---------------- layer-2 aggregation + fused epilogue, 4 edges/instr ----------------
// y23h row: halves 0..31 = mu-path, 32..63 = logvar-path. channel c = 4*l15+k.
__global__ __launch_bounds__(256) void k_agg2(const int* __restrict__ row_start,
                                              const int* __restrict__ cnt,
                                              const float* __restrict__ dis,
                                              const int* __restrict__ csr,
                                              const __half* __restrict__ y23h,
                                              const float* __restrict__ b2,
                                              const float* __restrict__ b3,
                                              const float* __restrict__ eps,
                                              float* __restrict__ out_z,
                                              float* __restrict__ out_mu,
                                              float* __restrict__ out_lv) {
    int node = (blockIdx.x * 256 + threadIdx.x) >> 6;
    int lane = threadIdx.x & 63;
    if (node >= NN) return;
    int g = lane >> 4, l15 = lane & 15;
    int start = row_start[node];
    int c = cnt[node];
    const float2* yb = (const float2*)y23h;
    float4 a0 = make_float4(0.f, 0.f, 0.f, 0.f);
    float4 a1 = make_float4(0.f, 0.f, 0.f, 0.f);
    int j = 0;
    for (; j + 8 <= c; j += 8) {
        int s0 = csr[start + j + g];
        int s1 = csr[start + j + 4 + g];
        float2 r0 = yb[(size_t)s0 * 16 + l15];
        float2 r1 = yb[(size_t)s1 * 16 + l15];
        float4 v0 = h4_to_f4(r0), v1 = h4_to_f4(r1);
        a0.x += v0.x; a0.y += v0.y; a0.z += v0.z; a0.w += v0.w;
        a1.x += v1.x; a1.y += v1.y; a1.z += v1.z; a1.w += v1.w;
    }
    for (; j < c; j += 4) {
        int pos = start + j + g;
        bool valid = (j + g) < c;
        pos = pos < NE ? pos : NE - 1;
        int s = csr[pos];
        s = valid ? s : node;
        float4 v = h4_to_f4(yb[(size_t)s * 16 + l15]);
        a0.x += valid ? v.x : 0.f; a0.y += valid ? v.y : 0.f;
        a0.z += valid ? v.z : 0.f; a0.w += valid ? v.w : 0.f;
    }
    float4 tot = make_float4(a0.x + a1.x, a0.y + a1.y, a0.z + a1.z, a0.w + a1.w);
    tot.x += __shfl_xor(tot.x, 16, 64); tot.x += __shfl_xor(tot.x, 32, 64);
    tot.y += __shfl_xor(tot.y, 16, 64); tot.y += __shfl_xor(tot.y, 32, 64);
    tot.z += __shfl_xor(tot.z, 16, 64); tot.z += __shfl_xor(tot.z, 32, 64);
    tot.w += __shfl_xor(tot.w, 16, 64); tot.w += __shfl_xor(tot.w, 32, 64);
    float4 sv = h4_to_f4(yb[(size_t)node * 16 + l15]);
    float dn = dis[node];
    // bias + relu; l15<8 -> mu channels 4*l15..+3 ; l15>=8 -> logvar channels 4*(l15-8)..+3
    float4 bias = (l15 < 8) ? ((const float4*)b2)[l15] : ((const float4*)b3)[l15 - 8];
    float4 val;
    val.x = fmaxf(dn * (tot.x + sv.x) + bias.x, 0.f);
    val.y = fmaxf(dn * (tot.y + sv.y) + bias.y, 0.f);
    val.z = fmaxf(dn * (tot.z + sv.z) + bias.z, 0.f);
    val.w = fmaxf(dn * (tot.w + sv.w) + bias.w, 0.f);
    // partner exchange: l15 ^ 8 pairs mu-quad with logvar-quad for same channels
    float4 other;
    other.x = __shfl_xor(val.x, 8, 64);
    other.y = __shfl_xor(val.y, 8, 64);
    other.z = __shfl_xor(val.z, 8, 64);
    other.w = __shfl_xor(val.w, 8, 64);
    if (g == 0) {
        if (l15 < 8) {
            size_t q = (size_t)node * 8 + l15;   // float4 index into [N,32]
            ((float4*)out_mu)[q] = val;
            float4 ev = ((const float4*)eps)[q];
            float4 z;
            z.x = ev.x * __expf(other.x) + val.x;
            z.y = ev.y * __expf(other.y) + val.y;
            z.z = ev.z * __expf(other.z) + val.z;
            z.w = ev.w * __expf(other.w) + val.w;
            ((float4*)out_z)[q] = z;
        } else {
            ((float4*)out_lv)[(size_t)node * 8 + (l15 - 8)] = val;
        }
    }
}

extern "C" void kernel_launch(void* const* d_in, const int* in_sizes, int n_in,
                              void* d_out, int out_size, void* d_ws, size_t ws_size,
                              hipStream_t stream) {
    const float* x   = (const float*)d_in[0];
    const int*   ei  = (const int*)d_in[1];   // [2, E]
    const int*   bat = (const int*)d_in[2];
    const float* W1  = (const float*)d_in[3];
    const float* b1  = (const float*)d_in[4];
    const float* W2  = (const float*)d_in[5];
    const float* b2  = (const float*)d_in[6];
    const float* W3  = (const float*)d_in[7];
    const float* b3  = (const float*)d_in[8];
    const float* eps = (const float*)d_in[9];

    const int* src = ei;
    const int* dst = ei + NE;

    float* out = (float*)d_out;
    float* out_z    = out;                               // [N,32]
    float* out_pool = out + (size_t)NN * H2;             // [G,7]
    float* out_mu   = out_pool + NG * D_IN;              // [N,32]
    float* out_lv   = out_mu + (size_t)NN * H2;          // [N,32]

    // workspace layout (4-byte words)
    int*    cnt       = (int*)d_ws;                      // N
    int*    row_start = cnt + NN;                        // N
    int*    cursor    = row_start + NN;                  // N
    int*    partials  = cursor + NN;                     // 512
    float*  dis       = (float*)(partials + 512);        // N
    int*    csr       = (int*)(dis + NN);                // NE ints
    __half* y1h       = (__half*)(csr + NE);             // N*64 halves
    float*  agg1      = (float*)(y1h + (size_t)NN * H1); // N*64 floats
    __half* y23h      = y1h;                             // alias: y1h dead after k_agg1

    hipMemsetAsync(cnt, 0, NN * sizeof(int), stream);

    k_hist <<<(NE + 255) / 256, 256, 0, stream>>>(dst, cnt);
    k_scan1<<<NB, 256, 0, stream>>>(cnt, partials);
    k_scan2<<<1, 512, 0, stream>>>(partials);
    k_scan3<<<NB, 256, 0, stream>>>(cnt, partials, row_start, cursor, dis);
    k_fill <<<(NE + 255) / 256, 256, 0, stream>>>(src, dst, cursor, csr);

    k_pool <<<NG, 256, 0, stream>>>(x, bat, out_pool);

    k_mm1  <<<(NN * H1 + 255) / 256, 256, 0, stream>>>(x, W1, dis, y1h);
    k_agg1 <<<(NN + 3) / 4, 256, 0, stream>>>(row_start, cnt, dis, csr, y1h, agg1);
    k_mm2  <<<(NN + 7) / 8, 256, 0, stream>>>(agg1, b1, W2, W3, dis, y23h);
    k_agg2 <<<(NN + 3) / 4, 256, 0, stream>>>(row_start, cnt, dis, csr, y23h,
                                              b2, b3, eps, out_z, out_mu, out_lv);
}

// Round 7
// 327.683 us; speedup vs baseline: 2.2015x; 1.3778x over previous
//
#include <hip/hip_runtime.h>
#include <hip/hip_bf16.h>
#include <hip/hip_fp16.h>

#define NN 100000
#define NE 1600000
#define D_IN 7
#define H1 64
#define H2 32
#define NG 64
#define TE 4096          // edges per bin tile
#define NTILE 391        // ceil(NE/TE)
#define BSH 9            // bucket = dst >> 9  (512 nodes/bucket)
#define NBUK 196         // ceil(NN/512)

// ---------------- bucket histogram ----------------
__global__ __launch_bounds__(256) void k_bcount(const int* __restrict__ dst,
                                                int* __restrict__ bucket_cnt) {
    __shared__ int h[NBUK];
    int t = threadIdx.x;
    for (int i = t; i < NBUK; i += 256) h[i] = 0;
    __syncthreads();
    int base = blockIdx.x * TE;
#pragma unroll
    for (int k = 0; k < TE / 256; k++) {
        int i = base + k * 256 + t;
        if (i < NE) atomicAdd(&h[dst[i] >> BSH], 1);
    }
    __syncthreads();
    for (int i = t; i < NBUK; i += 256) if (h[i]) atomicAdd(&bucket_cnt[i], h[i]);
}

// ---------------- scan bucket totals ----------------
__global__ void k_bscan(const int* __restrict__ bucket_cnt, int* __restrict__ bucket_base,
                        int* __restrict__ bucket_cursor, int* __restrict__ row_start) {
    __shared__ int s[256];
    int t = threadIdx.x;
    int v = (t < NBUK) ? bucket_cnt[t] : 0;
    s[t] = v;
    __syncthreads();
    for (int off = 1; off < 256; off <<= 1) {
        int add = (t >= off) ? s[t - off] : 0;
        __syncthreads();
        s[t] += add;
        __syncthreads();
    }
    if (t < NBUK) {
        int excl = s[t] - v;
        bucket_base[t] = excl;
        bucket_cursor[t] = excl;
    }
    if (t == 0) { bucket_base[NBUK] = NE; row_start[NN] = NE; }
}

// ---------------- bin edges into bucket-grouped staging (coalesced flush) ----------------
__global__ __launch_bounds__(256) void k_bin(const int* __restrict__ src,
                                             const int* __restrict__ dst,
                                             int* __restrict__ bucket_cursor,
                                             int2* __restrict__ staging) {
    __shared__ int hist[NBUK];
    __shared__ int startx[NBUK];
    __shared__ int runb[NBUK];
    __shared__ int cur[NBUK];
    __shared__ int sc[256];
    __shared__ int2 pairs[TE];
    int t = threadIdx.x;
    int base = blockIdx.x * TE;
    int tile_cnt = min(TE, NE - base);
    for (int i = t; i < NBUK; i += 256) hist[i] = 0;
    __syncthreads();
    int myd[TE / 256], mys[TE / 256];
#pragma unroll
    for (int k = 0; k < TE / 256; k++) {
        int i = base + k * 256 + t;
        if (i < NE) {
            myd[k] = dst[i]; mys[k] = src[i];
            atomicAdd(&hist[myd[k] >> BSH], 1);
        } else myd[k] = -1;
    }
    __syncthreads();
    int hv = (t < NBUK) ? hist[t] : 0;
    sc[t] = hv;
    __syncthreads();
    for (int off = 1; off < 256; off <<= 1) {
        int add = (t >= off) ? sc[t - off] : 0;
        __syncthreads();
        sc[t] += add;
        __syncthreads();
    }
    if (t < NBUK) {
        int ex = sc[t] - hv;
        startx[t] = ex;
        cur[t] = ex;
        if (hv > 0) runb[t] = atomicAdd(&bucket_cursor[t], hv);
    }
    __syncthreads();
#pragma unroll
    for (int k = 0; k < TE / 256; k++) {
        if (myd[k] >= 0) {
            int b = myd[k] >> BSH;
            int slot = atomicAdd(&cur[b], 1);
            pairs[slot] = make_int2(myd[k], mys[k]);
        }
    }
    __syncthreads();
    for (int i = t; i < tile_cnt; i += 256) {   // linear LDS -> mostly-contiguous global
        int2 p = pairs[i];
        int b = p.x >> BSH;
        staging[runb[b] + (i - startx[b])] = p;
    }
}

// ---------------- per-bucket CSR finalize: row offsets, dis, dense scatter ----------------
__global__ __launch_bounds__(512) void k_build(const int2* __restrict__ staging,
                                               const int* __restrict__ bucket_base,
                                               int* __restrict__ row_start,
                                               float* __restrict__ dis,
                                               int* __restrict__ csr) {
    __shared__ int cnt[512];
    __shared__ int offs[512];
    __shared__ int cur[512];
    int t = threadIdx.x;
    int nbase = blockIdx.x << BSH;
    int ebase = bucket_base[blockIdx.x], eend = bucket_base[blockIdx.x + 1];
    cnt[t] = 0;
    __syncthreads();
    for (int i = ebase + t; i < eend; i += 512)
        atomicAdd(&cnt[staging[i].x - nbase], 1);
    __syncthreads();
    int v = cnt[t];
    offs[t] = v;
    __syncthreads();
    for (int off = 1; off < 512; off <<= 1) {
        int add = (t >= off) ? offs[t - off] : 0;
        __syncthreads();
        offs[t] += add;
        __syncthreads();
    }
    int excl = offs[t] - v;
    cur[t] = excl;
    int node = nbase + t;
    if (node < NN) {
        row_start[node] = ebase + excl;
        dis[node] = rsqrtf((float)v + 1.0f);
    }
    __syncthreads();
    for (int i = ebase + t; i < eend; i += 512) {
        int2 p = staging[i];
        int pos = ebase + atomicAdd(&cur[p.x - nbase], 1);
        csr[pos] = p.y;          // stores confined to bucket's ~32KB csr window
    }
}

// ---------------- mean pool over sorted batch ----------------
__device__ int lower_bound_i(const int* a, int n, int v) {
    int lo = 0, hi = n;
    while (lo < hi) { int mid = (lo + hi) >> 1; if (a[mid] < v) lo = mid + 1; else hi = mid; }
    return lo;
}

__global__ void k_pool(const float* __restrict__ x, const int* __restrict__ batch,
                       float* __restrict__ outp) {
    __shared__ int bounds[2];
    __shared__ float red[256 * D_IN];
    int g = blockIdx.x, t = threadIdx.x;
    if (t == 0) {
        bounds[0] = lower_bound_i(batch, NN, g);
        bounds[1] = lower_bound_i(batch, NN, g + 1);
    }
    __syncthreads();
    int s = bounds[0], e = bounds[1];
    float acc[D_IN];
#pragma unroll
    for (int k = 0; k < D_IN; k++) acc[k] = 0.f;
    for (int n = s + t; n < e; n += 256) {
#pragma unroll
        for (int k = 0; k < D_IN; k++) acc[k] += x[n * D_IN + k];
    }
#pragma unroll
    for (int k = 0; k < D_IN; k++) red[t * D_IN + k] = acc[k];
    __syncthreads();
    if (t < D_IN) {
        float sum = 0.f;
        for (int i = 0; i < 256; i++) sum += red[i * D_IN + t];
        float cnt = (float)(e - s);
        outp[g * D_IN + t] = sum / fmaxf(cnt, 1.f);
    }
}

// ---------------- y1h = fp16( dis * (x @ W1) ) ----------------
__global__ void k_mm1(const float* __restrict__ x, const float* __restrict__ W1,
                      const float* __restrict__ dis, __half* __restrict__ y1h) {
    __shared__ float sW[D_IN * H1];
    int t = threadIdx.x;
    for (int i = t; i < D_IN * H1; i += 256) sW[i] = W1[i];
    __syncthreads();
    int idx = blockIdx.x * 256 + t;
    if (idx < NN * H1) {
        int n = idx >> 6, h = idx & 63;
        float a = 0.f;
#pragma unroll
        for (int k = 0; k < D_IN; k++) a += x[n * D_IN + k] * sW[k * H1 + h];
        y1h[idx] = __float2half(a * dis[n]);
    }
}

// convert 4 packed halves (as float2 raw) to float4
__device__ __forceinline__ float4 h4_to_f4(float2 r) {
    __half2 h0 = *reinterpret_cast<__half2*>(&r.x);
    __half2 h1 = *reinterpret_cast<__half2*>(&r.y);
    float2 f0 = __half22float2(h0);
    float2 f1 = __half22float2(h1);
    return make_float4(f0.x, f0.y, f1.x, f1.y);
}

// ---------------- layer-1 aggregation: wave per node, 4 edges/instr ----------------
__global__ __launch_bounds__(256) void k_agg1(const int* __restrict__ row_start,
                                              const float* __restrict__ dis,
                                              const int* __restrict__ csr,
                                              const __half* __restrict__ y1h,
                                              float* __restrict__ agg1) {
    int node = (blockIdx.x * 256 + threadIdx.x) >> 6;
    int lane = threadIdx.x & 63;
    if (node >= NN) return;
    int g = lane >> 4, l15 = lane & 15;
    int start = row_start[node];
    int c = row_start[node + 1] - start;
    const float2* yb = (const float2*)y1h;
    float4 a0 = make_float4(0.f, 0.f, 0.f, 0.f);
    float4 a1 = make_float4(0.f, 0.f, 0.f, 0.f);
    int j = 0;
    for (; j + 8 <= c; j += 8) {
        int s0 = csr[start + j + g];
        int s1 = csr[start + j + 4 + g];
        float2 r0 = yb[(size_t)s0 * 16 + l15];
        float2 r1 = yb[(size_t)s1 * 16 + l15];
        float4 v0 = h4_to_f4(r0), v1 = h4_to_f4(r1);
        a0.x += v0.x; a0.y += v0.y; a0.z += v0.z; a0.w += v0.w;
        a1.x += v1.x; a1.y += v1.y; a1.z += v1.z; a1.w += v1.w;
    }
    for (; j < c; j += 4) {
        int pos = start + j + g;
        bool valid = (j + g) < c;
        pos = pos < NE ? pos : NE - 1;
        int s = csr[pos];
        s = valid ? s : node;
        float4 v = h4_to_f4(yb[(size_t)s * 16 + l15]);
        a0.x += valid ? v.x : 0.f; a0.y += valid ? v.y : 0.f;
        a0.z += valid ? v.z : 0.f; a0.w += valid ? v.w : 0.f;
    }
    float4 tot = make_float4(a0.x + a1.x, a0.y + a1.y, a0.z + a1.z, a0.w + a1.w);
    tot.x += __shfl_xor(tot.x, 16, 64); tot.x += __shfl_xor(tot.x, 32, 64);
    tot.y += __shfl_xor(tot.y, 16, 64); tot.y += __shfl_xor(tot.y, 32, 64);
    tot.z += __shfl_xor(tot.z, 16, 64); tot.z += __shfl_xor(tot.z, 32, 64);
    tot.w += __shfl_xor(tot.w, 16, 64); tot.w += __shfl_xor(tot.w, 32, 64);
    float4 sv = h4_to_f4(yb[(size_t)node * 16 + l15]);
    float dn = dis[node];
    float4 outv = make_float4(dn * (tot.x + sv.x), dn * (tot.y + sv.y),
                              dn * (tot.z + sv.z), dn * (tot.w + sv.w));
    if (g == 0) ((float4*)(agg1 + (size_t)node * 64))[l15] = outv;
}

// ---------------- h1 = relu(agg1+b1); y23h = fp16( dis * (h1@W2 ‖ h1@W3) ) ----------------
__global__ void k_mm2(const float* __restrict__ agg1, const float* __restrict__ b1,
                      const float* __restrict__ W2, const float* __restrict__ W3,
                      const float* __restrict__ dis, __half* __restrict__ y23h) {
    __shared__ float sW2[H1 * H2];
    __shared__ float sW3[H1 * H2];
    __shared__ float sb1[H1];
    __shared__ float sh[8 * H1];
    int t = threadIdx.x;
    for (int i = t; i < H1 * H2; i += 256) { sW2[i] = W2[i]; sW3[i] = W3[i]; }
    if (t < H1) sb1[t] = b1[t];
    __syncthreads();
    int base_n = blockIdx.x * 8;
    for (int i = t; i < 8 * H1; i += 256) {
        int n = base_n + (i >> 6);
        sh[i] = (n < NN) ? fmaxf(agg1[n * H1 + (i & 63)] + sb1[i & 63], 0.f) : 0.f;
    }
    __syncthreads();
    int n = base_n + (t >> 5), h = t & 31;
    if (n < NN) {
        float a2 = 0.f, a3 = 0.f;
        const float* hr = &sh[(t >> 5) * H1];
#pragma unroll
        for (int k = 0; k < H1; k++) {
            float hv = hr[k];
            a2 += hv * sW2[k * H2 + h];
            a3 += hv * sW3[k * H2 + h];
        }
        float d = dis[n];
        y23h[n * 64 + h]      = __float2half(d * a2);
        y23h[n * 64 + 32 + h] = __float2half(d * a3);
    }
}

// ---------------- layer-2 aggregation + fused epilogue, 4 edges/instr ----------------
__global__ __launch_bounds__(256) void k_agg2(const int* __restrict__ row_start,
                                              const float* __restrict__ dis,
                                              const int* __restrict__ csr,
                                              const __half* __restrict__ y23h,
                                              const float* __restrict__ b2,
                                              const float* __restrict__ b3,
                                              const float* __restrict__ eps,
                                              float* __restrict__ out_z,
                                              float* __restrict__ out_mu,
                                              float* __restrict__ out_lv) {
    int node = (blockIdx.x * 256 + threadIdx.x) >> 6;
    int lane = threadIdx.x & 63;
    if (node >= NN) return;
    int g = lane >> 4, l15 = lane & 15;
    int start = row_start[node];
    int c = row_start[node + 1] - start;
    const float2* yb = (const float2*)y23h;
    float4 a0 = make_float4(0.f, 0.f, 0.f, 0.f);
    float4 a1 = make_float4(0.f, 0.f, 0.f, 0.f);
    int j = 0;
    for (; j + 8 <= c; j += 8) {
        int s0 = csr[start + j + g];
        int s1 = csr[start + j + 4 + g];
        float2 r0 = yb[(size_t)s0 * 16 + l15];
        float2 r1 = yb[(size_t)s1 * 16 + l15];
        float4 v0 = h4_to_f4(r0), v1 = h4_to_f4(r1);
        a0.x += v0.x; a0.y += v0.y; a0.z += v0.z; a0.w += v0.w;
        a1.x += v1.x; a1.y += v1.y; a1.z += v1.z; a1.w += v1.w;
    }
    for (; j < c; j += 4) {
        int pos = start + j + g;
        bool valid = (j + g) < c;
        pos = pos < NE ? pos : NE - 1;
        int s = csr[pos];
        s = valid ? s : node;
        float4 v = h4_to_f4(yb[(size_t)s * 16 + l15]);
        a0.x += valid ? v.x : 0.f; a0.y += valid ? v.y : 0.f;
        a0.z += valid ? v.z : 0.f; a0.w += valid ? v.w : 0.f;
    }
    float4 tot = make_float4(a0.x + a1.x, a0.y + a1.y, a0.z + a1.z, a0.w + a1.w);
    tot.x += __shfl_xor(tot.x, 16, 64); tot.x += __shfl_xor(tot.x, 32, 64);
    tot.y += __shfl_xor(tot.y, 16, 64); tot.y += __shfl_xor(tot.y, 32, 64);
    tot.z += __shfl_xor(tot.z, 16, 64); tot.z += __shfl_xor(tot.z, 32, 64);
    tot.w += __shfl_xor(tot.w, 16, 64); tot.w += __shfl_xor(tot.w, 32, 64);
    float4 sv = h4_to_f4(yb[(size_t)node * 16 + l15]);
    float dn = dis[node];
    float4 bias = (l15 < 8) ? ((const float4*)b2)[l15] : ((const float4*)b3)[l15 - 8];
    float4 val;
    val.x = fmaxf(dn * (tot.x + sv.x) + bias.x, 0.f);
    val.y = fmaxf(dn * (tot.y + sv.y) + bias.y, 0.f);
    val.z = fmaxf(dn * (tot.z + sv.z) + bias.z, 0.f);
    val.w = fmaxf(dn * (tot.w + sv.w) + bias.w, 0.f);
    float4 other;
    other.x = __shfl_xor(val.x, 8, 64);
    other.y = __shfl_xor(val.y, 8, 64);
    other.z = __shfl_xor(val.z, 8, 64);
    other.w = __shfl_xor(val.w, 8, 64);
    if (g == 0) {
        if (l15 < 8) {
            size_t q = (size_t)node * 8 + l15;
            ((float4*)out_mu)[q] = val;
            float4 ev = ((const float4*)eps)[q];
            float4 z;
            z.x = ev.x * __expf(other.x) + val.x;
            z.y = ev.y * __expf(other.y) + val.y;
            z.z = ev.z * __expf(other.z) + val.z;
            z.w = ev.w * __expf(other.w) + val.w;
            ((float4*)out_z)[q] = z;
        } else {
            ((float4*)out_lv)[(size_t)node * 8 + (l15 - 8)] = val;
        }
    }
}

extern "C" void kernel_launch(void* const* d_in, const int* in_sizes, int n_in,
                              void* d_out, int out_size, void* d_ws, size_t ws_size,
                              hipStream_t stream) {
    const float* x   = (const float*)d_in[0];
    const int*   ei  = (const int*)d_in[1];   // [2, E]
    const int*   bat = (const int*)d_in[2];
    const float* W1  = (const float*)d_in[3];
    const float* b1  = (const float*)d_in[4];
    const float* W2  = (const float*)d_in[5];
    const float* b2  = (const float*)d_in[6];
    const float* W3  = (const float*)d_in[7];
    const float* b3  = (const float*)d_in[8];
    const float* eps = (const float*)d_in[9];

    const int* src = ei;
    const int* dst = ei + NE;

    float* out = (float*)d_out;
    float* out_z    = out;                               // [N,32]
    float* out_pool = out + (size_t)NN * H2;             // [G,7]
    float* out_mu   = out_pool + NG * D_IN;              // [N,32]
    float* out_lv   = out_mu + (size_t)NN * H2;          // [N,32]

    // workspace layout (4-byte words); staging kept 8B-aligned
    int*    bucket_cnt    = (int*)d_ws;                      // 256
    int*    bucket_base   = bucket_cnt + 256;                // 256 (NBUK+1 used)
    int*    bucket_cursor = bucket_base + 256;               // 256
    int*    row_start     = bucket_cursor + 256;             // NN+2 (pad to even)
    float*  dis           = (float*)(row_start + NN + 2);    // NN
    int2*   staging       = (int2*)(dis + NN);               // NE int2 (8B-aligned: 768+100002+100000 even)
    int*    csr           = (int*)(staging + NE);            // NE
    __half* y1h           = (__half*)(csr + NE);             // NN*64 halves
    float*  agg1          = (float*)(y1h + (size_t)NN * H1); // NN*64 floats
    __half* y23h          = y1h;                             // alias: y1h dead after k_agg1

    hipMemsetAsync(bucket_cnt, 0, 256 * sizeof(int), stream);

    k_bcount<<<NTILE, 256, 0, stream>>>(dst, bucket_cnt);
    k_bscan <<<1, 256, 0, stream>>>(bucket_cnt, bucket_base, bucket_cursor, row_start);
    k_bin   <<<NTILE, 256, 0, stream>>>(src, dst, bucket_cursor, staging);
    k_build <<<NBUK, 512, 0, stream>>>(staging, bucket_base, row_start, dis, csr);

    k_pool  <<<NG, 256, 0, stream>>>(x, bat, out_pool);

    k_mm1   <<<(NN * H1 + 255) / 256, 256, 0, stream>>>(x, W1, dis, y1h);
    k_agg1  <<<(NN + 3) / 4, 256, 0, stream>>>(row_start, dis, csr, y1h, agg1);
    k_mm2   <<<(NN + 7) / 8, 256, 0, stream>>>(agg1, b1, W2, W3, dis, y23h);
    k_agg2  <<<(NN + 3) / 4, 256, 0, stream>>>(row_start, dis, csr, y23h,
                                               b2, b3, eps, out_z, out_mu, out_lv);
}